// Round 6
// baseline (930.548 us; speedup 1.0000x reference)
//
#include <hip/hip_runtime.h>
#include <cmath>

#define TT   6
#define NB   128
#define DIM  192
#define SCALE 0.17677669529663687f

typedef __attribute__((ext_vector_type(8))) short v8s;
typedef __attribute__((ext_vector_type(4))) float v4f;

__device__ __forceinline__ short f2bf(float f) {
  union { float f; unsigned u; } v; v.f = f;
  unsigned r = v.u + 0x7fffu + ((v.u >> 16) & 1u);
  return (short)(r >> 16);
}
__device__ __forceinline__ void fence() {
  __asm__ volatile("s_waitcnt lgkmcnt(0)" ::: "memory");
}

// ---- fused prep: bf16 weight conversion + sine position table, one launch ----
__global__ void prep_kernel(const float* __restrict__ Wqkv, const float* __restrict__ Wproj,
                            const float* __restrict__ W1, const float* __restrict__ W2,
                            short* __restrict__ dWqkv, short* __restrict__ dWproj,
                            short* __restrict__ dW1, short* __restrict__ dW2,
                            float* __restrict__ pos) {
  int idx = blockIdx.x * 256 + threadIdx.x;
  const float* src = nullptr; short* dst = nullptr; int off = 0;
  if (idx < 27648)      { src = Wqkv;  dst = dWqkv;  off = idx; }
  else if (idx < 46080) { src = Wproj; dst = dWproj; off = idx - 27648; }
  else if (idx < 55296) { src = W1;    dst = dW1;    off = idx - 46080; }
  else if (idx < 64512) { src = W2;    dst = dW2;    off = idx - 55296; }
  else if (idx < 67584) {
    int p0 = (idx - 64512) * 4;
    float4 r;
    float* rp = (float*)&r;
#pragma unroll
    for (int jj = 0; jj < 4; jj++) {
      int p = p0 + jj;
      int row = p / 192, c = p - row * 192;
      int e  = (c < 96) ? (row >> 3) : (row & 7);
      int cc = (c < 96) ? c : c - 96;
      int m = cc >> 1;
      float embed = (float)(e + 1) * (6.283185307179586f / 8.000001f);
      float dt = powf(10000.0f, (float)m * (1.0f / 48.0f));
      float ang = embed / dt;
      rp[jj] = (cc & 1) ? cosf(ang) : sinf(ang);
    }
    *(float4*)(pos + p0) = r;
    return;
  } else return;
  const float* s = src + off * 4;
  short4 r;
  r.x = f2bf(s[0]); r.y = f2bf(s[1]); r.z = f2bf(s[2]); r.w = f2bf(s[3]);
  *(short4*)(dst + off * 4) = r;
}

// ---- QKV pre-kernel: one block per (b,t). Q,K row-major [hw][ch]; V transposed [ch][hw].
// Grid swizzled with the SAME XCD mapping as fused_all (confirmed working in r4:
// FETCH dropped to 78MB once spill traffic was removed).
__global__ __launch_bounds__(256) void qkv_kernel(
    const float* __restrict__ x, const float* __restrict__ pos,
    const short* __restrict__ Wqkv_bf,
    short* __restrict__ Qb, short* __restrict__ Kb, short* __restrict__ Vtb) {
  __shared__ short XP[64 * 200];
  int bid = blockIdx.x;
  int xcd = bid & 7, idx = bid >> 3;   // 96 blocks per XCD
  int bq = idx / TT;
  int b = xcd * 16 + bq, t = idx - bq * TT;
  int tid = threadIdx.x, w = tid >> 6, lane = tid & 63;
  int l15 = lane & 15, quad = lane >> 4;
  const float* xrow = x + (size_t)(b * (TT * 64) + t * 64) * DIM;
  for (int c = tid; c < 64 * 24; c += 256) {
    int row = c / 24, col8 = (c - (c / 24) * 24) * 8;
    const float* xs = xrow + row * DIM + col8;
    const float* pp = pos + row * DIM + col8;
    v8s r8;
#pragma unroll
    for (int jj = 0; jj < 8; jj++) r8[jj] = f2bf(xs[jj] + pp[jj]);
    *(v8s*)(XP + row * 200 + col8) = r8;
  }
  __syncthreads();
  const v4f vzero = {0.f, 0.f, 0.f, 0.f};
  size_t obase = (size_t)(b * TT + t) * 64 * DIM;
#pragma unroll
  for (int cti = 0; cti < 9; cti++) {
    int r0 = w * 144 + cti * 16;
    v4f acc[4] = {vzero, vzero, vzero, vzero};
#pragma unroll
    for (int ks = 0; ks < 6; ks++) {
      v8s a = *(const v8s*)(Wqkv_bf + (size_t)(r0 + l15) * 192 + ks * 32 + quad * 8);
#pragma unroll
      for (int nt = 0; nt < 4; nt++) {
        v8s bb = *(const v8s*)(XP + (nt * 16 + l15) * 200 + ks * 32 + quad * 8);
        acc[nt] = __builtin_amdgcn_mfma_f32_16x16x32_bf16(a, bb, acc[nt], 0, 0, 0);
      }
    }
    int R = r0 + quad * 4;
#pragma unroll
    for (int nt = 0; nt < 4; nt++) {
      int hw = nt * 16 + l15;
      if (R < 192) {
        short4 s;
        s.x = f2bf(acc[nt][0] * SCALE); s.y = f2bf(acc[nt][1] * SCALE);
        s.z = f2bf(acc[nt][2] * SCALE); s.w = f2bf(acc[nt][3] * SCALE);
        *(short4*)(Qb + obase + (size_t)hw * 192 + R) = s;
      } else if (R < 384) {
        short4 s;
        s.x = f2bf(acc[nt][0]); s.y = f2bf(acc[nt][1]);
        s.z = f2bf(acc[nt][2]); s.w = f2bf(acc[nt][3]);
        *(short4*)(Kb + obase + (size_t)hw * 192 + (R - 192)) = s;
      } else {
#pragma unroll
        for (int r = 0; r < 4; r++)
          Vtb[obase + (size_t)(R - 384 + r) * 64 + hw] = f2bf(acc[nt][r]);
      }
    }
  }
}

// ---- main fused kernel: one block per (i,b), 512 threads (8 waves).
// r1 structure (y1x register hoist, Pl LDS transpose -- best measured at 453us)
// with the barrier chain cut 6/j -> 4/j:
//  - gelu output h goes to separate HB buffer (no barrier between G2 reads and h writes)
//  - G3(j) and attn(j+1) share one barrier-free region (independent resources:
//    HB+weights vs SP+Pl+global K/V) so waves drift and overlap latencies.
// __launch_bounds__(512,4): 128-reg cap; (512,6) proved to spill (r2/r3: +400MB scratch).
__global__ __launch_bounds__(512, 4) void fused_all(
    const float* __restrict__ x,
    const short* __restrict__ Qb, const short* __restrict__ Kb,
    const short* __restrict__ Vtb,
    const short* __restrict__ Wproj_bf, const short* __restrict__ W1_bf,
    const short* __restrict__ W2_bf,
    const float* __restrict__ bproj, const float* __restrict__ gamma,
    const float* __restrict__ beta, const float* __restrict__ b1,
    const float* __restrict__ b2,
    float* __restrict__ out) {
  __shared__ short SP[64 * 200];     // Xi staging / o / y1n: [hw][ch]; f32 acc staging in epilogue
  __shared__ short HB[64 * 200];     // gelu output h: [hw][ch]
  __shared__ short Pl[8][16 * 72];   // per-wave P: [q][hw_k]
  __shared__ float LNp[64][4][2];    // LN partials: [hw][wc][s1,s2]

  // XCD swizzle: 6 i-blocks sharing b land on one XCD (shared Q/K/V in its L2)
  int bid = blockIdx.x;
  int xcd = bid & 7, idx6 = bid >> 3;
  int bq = idx6 / TT;
  int b = xcd * 16 + bq, i = idx6 - bq * TT;

  int tid = threadIdx.x, w = tid >> 6, lane = tid & 63;
  int l15 = lane & 15, quad = lane >> 4;
  int wc = w & 3, wh = w >> 2;
  int cb = wc * 48;
  const v4f vzero = {0.f, 0.f, 0.f, 0.f};

  // ---- stage Xi (x.view reinterpretation rows) as bf16 into SP ----
  const float* xi = x + (size_t)(i * NB + b) * 64 * DIM;
  for (int c = tid; c < 64 * 24; c += 512) {
    int row = c / 24, col8 = (c - (c / 24) * 24) * 8;
    const float* xs = xi + row * DIM + col8;
    v8s r8;
#pragma unroll
    for (int jj = 0; jj < 8; jj++) r8[jj] = f2bf(xs[jj]);
    *(v8s*)(SP + row * 200 + col8) = r8;
  }

  // ---- hoist Q fragments (j-invariant): wave's 16 q-rows x its 3 heads ----
  const short* Qi = Qb + (size_t)(b * TT + i) * 64 * DIM;
  v8s qa[3];
#pragma unroll
  for (int hh = 0; hh < 3; hh++)
    qa[hh] = *(const v8s*)(Qi + (size_t)(wc * 16 + l15) * 192 + (wh * 3 + hh) * 32 + quad * 8);

  v4f acc[3][2];
#pragma unroll
  for (int cti = 0; cti < 3; cti++)
#pragma unroll
    for (int nt = 0; nt < 2; nt++) acc[cti][nt] = vzero;

  __syncthreads();                   // Xi staged

  // ---- y1x = Wproj[:,192:384] . Xi^T (j-invariant half of G1, in registers) ----
  v4f y1x[3][2];
#pragma unroll
  for (int cti = 0; cti < 3; cti++)
#pragma unroll
    for (int nt = 0; nt < 2; nt++) y1x[cti][nt] = vzero;
#pragma unroll
  for (int ks = 0; ks < 6; ks++) {
    v8s bxi[2];
#pragma unroll
    for (int nt = 0; nt < 2; nt++)
      bxi[nt] = *(const v8s*)(SP + (wh * 32 + nt * 16 + l15) * 200 + ks * 32 + quad * 8);
#pragma unroll
    for (int cti = 0; cti < 3; cti++) {
      v8s a = *(const v8s*)(Wproj_bf + (size_t)(cb + cti * 16 + l15) * 384 + 192 + ks * 32 + quad * 8);
#pragma unroll
      for (int nt = 0; nt < 2; nt++)
        y1x[cti][nt] = __builtin_amdgcn_mfma_f32_16x16x32_bf16(a, bxi[nt], y1x[cti][nt], 0, 0, 0);
    }
  }
  __syncthreads();                   // y1x SP reads done; SP free for o

  // ---- attention for one (Kj, Vj): writes o into SP ----
  auto attn = [&](const short* Kj, const short* Vj) {
#pragma unroll
    for (int hh = 0; hh < 3; hh++) {
      int h = wh * 3 + hh;
      v4f S[4];
#pragma unroll
      for (int cta = 0; cta < 4; cta++) {
        v8s akq = *(const v8s*)(Kj + (size_t)(cta * 16 + l15) * 192 + h * 32 + quad * 8);
        S[cta] = __builtin_amdgcn_mfma_f32_16x16x32_bf16(akq, qa[hh], vzero, 0, 0, 0);
      }
      float mx = -1e30f;
#pragma unroll
      for (int cta = 0; cta < 4; cta++)
#pragma unroll
        for (int r = 0; r < 4; r++) mx = fmaxf(mx, S[cta][r]);
      mx = fmaxf(mx, __shfl_xor(mx, 16, 64));
      mx = fmaxf(mx, __shfl_xor(mx, 32, 64));
      float sum = 0.f;
#pragma unroll
      for (int cta = 0; cta < 4; cta++)
#pragma unroll
        for (int r = 0; r < 4; r++) {
          float e = __expf(S[cta][r] - mx);
          S[cta][r] = e; sum += e;
        }
      sum += __shfl_xor(sum, 16, 64);
      sum += __shfl_xor(sum, 32, 64);
      float inv = 1.0f / sum;
#pragma unroll
      for (int cta = 0; cta < 4; cta++) {
        short4 s;
        s.x = f2bf(S[cta][0] * inv); s.y = f2bf(S[cta][1] * inv);
        s.z = f2bf(S[cta][2] * inv); s.w = f2bf(S[cta][3] * inv);
        *(short4*)(&Pl[w][l15 * 72 + cta * 16 + quad * 4]) = s;
      }
      fence();
      v8s bp0 = *(const v8s*)(&Pl[w][l15 * 72 + quad * 8]);
      v8s bp1 = *(const v8s*)(&Pl[w][l15 * 72 + 32 + quad * 8]);
#pragma unroll
      for (int ct2 = 0; ct2 < 2; ct2++) {
        v8s av0 = *(const v8s*)(Vj + (size_t)(h * 32 + ct2 * 16 + l15) * 64 + quad * 8);
        v8s av1 = *(const v8s*)(Vj + (size_t)(h * 32 + ct2 * 16 + l15) * 64 + 32 + quad * 8);
        v4f o = __builtin_amdgcn_mfma_f32_16x16x32_bf16(av0, bp0, vzero, 0, 0, 0);
        o = __builtin_amdgcn_mfma_f32_16x16x32_bf16(av1, bp1, o, 0, 0, 0);
        short4 s;
        s.x = f2bf(o[0]); s.y = f2bf(o[1]); s.z = f2bf(o[2]); s.w = f2bf(o[3]);
        *(short4*)(&SP[(wc * 16 + l15) * 200 + h * 32 + ct2 * 16 + quad * 4]) = s;
      }
      fence();
    }
  };

  const short* KB0 = Kb + (size_t)(b * TT) * 64 * DIM;
  const short* VB0 = Vtb + (size_t)(b * TT) * 64 * DIM;
  attn(KB0, VB0);                    // j = 0 prologue

  for (int j = 0; j < TT; j++) {
    __syncthreads();               // A: o_j ready (attn done) + G3(j-1) HB reads done

    // ---- G1: y1 = y1x + Wproj[:,0:192] . o^T ----
    v4f y1[3][2];
#pragma unroll
    for (int cti = 0; cti < 3; cti++)
#pragma unroll
      for (int nt = 0; nt < 2; nt++) y1[cti][nt] = y1x[cti][nt];
#pragma unroll
    for (int ks = 0; ks < 6; ks++) {
      v8s bo[2];
#pragma unroll
      for (int nt = 0; nt < 2; nt++)
        bo[nt] = *(const v8s*)(SP + (wh * 32 + nt * 16 + l15) * 200 + ks * 32 + quad * 8);
#pragma unroll
      for (int cti = 0; cti < 3; cti++) {
        v8s a = *(const v8s*)(Wproj_bf + (size_t)(cb + cti * 16 + l15) * 384 + ks * 32 + quad * 8);
#pragma unroll
        for (int nt = 0; nt < 2; nt++)
          y1[cti][nt] = __builtin_amdgcn_mfma_f32_16x16x32_bf16(a, bo[nt], y1[cti][nt], 0, 0, 0);
      }
    }
    // + bproj; LN partials
#pragma unroll
    for (int cti = 0; cti < 3; cti++) {
      float4 bp4 = *(const float4*)(bproj + cb + cti * 16 + quad * 4);
#pragma unroll
      for (int nt = 0; nt < 2; nt++) {
        y1[cti][nt][0] += bp4.x; y1[cti][nt][1] += bp4.y;
        y1[cti][nt][2] += bp4.z; y1[cti][nt][3] += bp4.w;
      }
    }
#pragma unroll
    for (int nt = 0; nt < 2; nt++) {
      float s1 = 0.f, s2 = 0.f;
#pragma unroll
      for (int cti = 0; cti < 3; cti++)
#pragma unroll
        for (int r = 0; r < 4; r++) { float v = y1[cti][nt][r]; s1 += v; s2 += v * v; }
      s1 += __shfl_xor(s1, 16, 64); s2 += __shfl_xor(s2, 16, 64);
      s1 += __shfl_xor(s1, 32, 64); s2 += __shfl_xor(s2, 32, 64);
      if (quad == 0) {
        LNp[wh * 32 + nt * 16 + l15][wc][0] = s1;
        LNp[wh * 32 + nt * 16 + l15][wc][1] = s2;
      }
    }
    __syncthreads();               // B: partials visible; G1 SP reads done
    float mu[2], rs[2];
#pragma unroll
    for (int nt = 0; nt < 2; nt++) {
      int row = wh * 32 + nt * 16 + l15;
      float s1 = 0.f, s2 = 0.f;
#pragma unroll
      for (int ww = 0; ww < 4; ww++) { s1 += LNp[row][ww][0]; s2 += LNp[row][ww][1]; }
      float m = s1 * (1.0f / 192.0f);
      mu[nt] = m; rs[nt] = rsqrtf(s2 * (1.0f / 192.0f) - m * m + 1e-5f);
    }
#pragma unroll
    for (int cti = 0; cti < 3; cti++) {
      float4 g4 = *(const float4*)(gamma + cb + cti * 16 + quad * 4);
      float4 be4 = *(const float4*)(beta + cb + cti * 16 + quad * 4);
#pragma unroll
      for (int nt = 0; nt < 2; nt++) {
        short4 s;
        s.x = f2bf((y1[cti][nt][0] - mu[nt]) * rs[nt] * g4.x + be4.x);
        s.y = f2bf((y1[cti][nt][1] - mu[nt]) * rs[nt] * g4.y + be4.y);
        s.z = f2bf((y1[cti][nt][2] - mu[nt]) * rs[nt] * g4.z + be4.z);
        s.w = f2bf((y1[cti][nt][3] - mu[nt]) * rs[nt] * g4.w + be4.w);
        *(short4*)(&SP[(wh * 32 + nt * 16 + l15) * 200 + cb + cti * 16 + quad * 4]) = s;
      }
    }
    __syncthreads();               // C: y1n ready

    // ---- G2: y2 = W1 . y1n^T ; gelu -> HB (separate buffer: no barrier between) ----
    v4f y2[3][2];
#pragma unroll
    for (int cti = 0; cti < 3; cti++)
#pragma unroll
      for (int nt = 0; nt < 2; nt++) y2[cti][nt] = vzero;
#pragma unroll
    for (int ks = 0; ks < 6; ks++) {
      v8s bh[2];
#pragma unroll
      for (int nt = 0; nt < 2; nt++)
        bh[nt] = *(const v8s*)(SP + (wh * 32 + nt * 16 + l15) * 200 + ks * 32 + quad * 8);
#pragma unroll
      for (int cti = 0; cti < 3; cti++) {
        v8s a = *(const v8s*)(W1_bf + (size_t)(cb + cti * 16 + l15) * 192 + ks * 32 + quad * 8);
#pragma unroll
        for (int nt = 0; nt < 2; nt++)
          y2[cti][nt] = __builtin_amdgcn_mfma_f32_16x16x32_bf16(a, bh[nt], y2[cti][nt], 0, 0, 0);
      }
    }
#pragma unroll
    for (int cti = 0; cti < 3; cti++) {
      float4 b14 = *(const float4*)(b1 + cb + cti * 16 + quad * 4);
#pragma unroll
      for (int nt = 0; nt < 2; nt++) {
        float vv[4] = {y2[cti][nt][0] + b14.x, y2[cti][nt][1] + b14.y,
                       y2[cti][nt][2] + b14.z, y2[cti][nt][3] + b14.w};
        short sv[4];
#pragma unroll
        for (int r = 0; r < 4; r++) {
          float v = vv[r];
          float t = 0.79788456080286536f * (v + 0.044715f * v * v * v);
          float e = __expf(2.0f * t);
          float th = 1.0f - 2.0f / (e + 1.0f);
          sv[r] = f2bf(0.5f * v * (1.0f + th));
        }
        short4 s;
        s.x = sv[0]; s.y = sv[1]; s.z = sv[2]; s.w = sv[3];
        *(short4*)(&HB[(wh * 32 + nt * 16 + l15) * 200 + cb + cti * 16 + quad * 4]) = s;
      }
    }
    __syncthreads();               // D: h ready; G2 SP reads done -> SP free

    // ---- merged region: G3(j) from HB || attn(j+1) into SP ----
#pragma unroll
    for (int ks = 0; ks < 6; ks++) {
      v8s bh[2];
#pragma unroll
      for (int nt = 0; nt < 2; nt++)
        bh[nt] = *(const v8s*)(HB + (wh * 32 + nt * 16 + l15) * 200 + ks * 32 + quad * 8);
#pragma unroll
      for (int cti = 0; cti < 3; cti++) {
        v8s a = *(const v8s*)(W2_bf + (size_t)(cb + cti * 16 + l15) * 192 + ks * 32 + quad * 8);
#pragma unroll
        for (int nt = 0; nt < 2; nt++)
          acc[cti][nt] = __builtin_amdgcn_mfma_f32_16x16x32_bf16(a, bh[nt], acc[cti][nt], 0, 0, 0);
      }
    }
    if (j < TT - 1) {
      attn(Kb + (size_t)(b * TT + j + 1) * 64 * DIM,
           Vtb + (size_t)(b * TT + j + 1) * 64 * DIM);
    }
  }

  // ---- epilogue: stage acc/6 to LDS (f32), write full contiguous rows ----
  float* SPf = (float*)SP;
#pragma unroll
  for (int pass = 0; pass < 2; pass++) {
    __syncthreads();
    if (wh == pass) {
#pragma unroll
      for (int cti = 0; cti < 3; cti++)
#pragma unroll
        for (int nt = 0; nt < 2; nt++) {
          float4 o4;
          o4.x = acc[cti][nt][0] * (1.0f / 6.0f);
          o4.y = acc[cti][nt][1] * (1.0f / 6.0f);
          o4.z = acc[cti][nt][2] * (1.0f / 6.0f);
          o4.w = acc[cti][nt][3] * (1.0f / 6.0f);
          *(float4*)(&SPf[(nt * 16 + l15) * 196 + cb + cti * 16 + quad * 4]) = o4;
        }
    }
    __syncthreads();
    for (int c = tid; c < 1536; c += 512) {
      int r32 = c / 48, col4 = (c - r32 * 48) * 4;
      int row = pass * 32 + r32;
      size_t nrow = (size_t)b * 384 + (size_t)i * 64 + row;
      float4 xv = *(const float4*)(x + nrow * DIM + col4);
      float4 b24 = *(const float4*)(b2 + col4);
      float4 av = *(const float4*)(&SPf[r32 * 196 + col4]);
      float4 o4;
      o4.x = xv.x + av.x + b24.x;
      o4.y = xv.y + av.y + b24.y;
      o4.z = xv.z + av.z + b24.z;
      o4.w = xv.w + av.w + b24.w;
      *(float4*)(out + nrow * 384 + col4) = xv;             // x half bit-exact
      *(float4*)(out + nrow * 384 + 192 + col4) = o4;
    }
  }
}

extern "C" void kernel_launch(void* const* d_in, const int* in_sizes, int n_in,
                              void* d_out, int out_size, void* d_ws, size_t ws_size,
                              hipStream_t stream) {
  (void)in_sizes; (void)n_in; (void)out_size; (void)ws_size;
  const float* x     = (const float*)d_in[0];
  const float* Wqkv  = (const float*)d_in[1];
  const float* Wproj = (const float*)d_in[2];
  const float* bproj = (const float*)d_in[3];
  const float* gamma = (const float*)d_in[4];
  const float* beta  = (const float*)d_in[5];
  const float* W1    = (const float*)d_in[6];
  const float* b1    = (const float*)d_in[7];
  const float* W2    = (const float*)d_in[8];
  const float* b2    = (const float*)d_in[9];
  float* out = (float*)d_out;

  // workspace: weights bf16 + pos f32 + Q/K/Vt bf16
  short* Wqkv_bf  = (short*)d_ws;                 // 576*192
  short* Wproj_bf = Wqkv_bf + 110592;             // 192*384
  short* W1_bf    = Wproj_bf + 73728;             // 192*192
  short* W2_bf    = W1_bf + 36864;                // 192*192
  float* pos_f    = (float*)(W2_bf + 36864);      // 64*192 f32
  short* Qb       = (short*)(pos_f + 12288);      // [b][t][hw][ch]
  short* Kb       = Qb + 9437184;                 // [b][t][hw][ch]
  short* Vtb      = Kb + 9437184;                 // [b][t][ch][hw]

  prep_kernel<<<dim3(264), dim3(256), 0, stream>>>(
      Wqkv, Wproj, W1, W2, Wqkv_bf, Wproj_bf, W1_bf, W2_bf, pos_f);
  qkv_kernel<<<dim3(TT * NB), dim3(256), 0, stream>>>(x, pos_f, Wqkv_bf, Qb, Kb, Vtb);
  fused_all<<<dim3(TT * NB), dim3(512), 0, stream>>>(
      x, Qb, Kb, Vtb, Wproj_bf, W1_bf, W2_bf, bproj, gamma, beta, b1, b2, out);
}

// Round 7
// 925.976 us; speedup vs baseline: 1.0049x; 1.0049x over previous
//
#include <hip/hip_runtime.h>
#include <cmath>

#define TT   6
#define NB   128
#define DIM  192
#define SCALE 0.17677669529663687f

typedef __attribute__((ext_vector_type(8))) short v8s;
typedef __attribute__((ext_vector_type(4))) float v4f;

__device__ __forceinline__ short f2bf(float f) {
  union { float f; unsigned u; } v; v.f = f;
  unsigned r = v.u + 0x7fffu + ((v.u >> 16) & 1u);
  return (short)(r >> 16);
}
__device__ __forceinline__ void fence() {
  __asm__ volatile("s_waitcnt lgkmcnt(0)" ::: "memory");
}

// ---- fused prep: bf16 weight conversion + sine position table, one launch ----
__global__ void prep_kernel(const float* __restrict__ Wqkv, const float* __restrict__ Wproj,
                            const float* __restrict__ W1, const float* __restrict__ W2,
                            short* __restrict__ dWqkv, short* __restrict__ dWproj,
                            short* __restrict__ dW1, short* __restrict__ dW2,
                            float* __restrict__ pos) {
  int idx = blockIdx.x * 256 + threadIdx.x;
  const float* src = nullptr; short* dst = nullptr; int off = 0;
  if (idx < 27648)      { src = Wqkv;  dst = dWqkv;  off = idx; }
  else if (idx < 46080) { src = Wproj; dst = dWproj; off = idx - 27648; }
  else if (idx < 55296) { src = W1;    dst = dW1;    off = idx - 46080; }
  else if (idx < 64512) { src = W2;    dst = dW2;    off = idx - 55296; }
  else if (idx < 67584) {
    int p0 = (idx - 64512) * 4;
    float4 r;
    float* rp = (float*)&r;
#pragma unroll
    for (int jj = 0; jj < 4; jj++) {
      int p = p0 + jj;
      int row = p / 192, c = p - row * 192;
      int e  = (c < 96) ? (row >> 3) : (row & 7);
      int cc = (c < 96) ? c : c - 96;
      int m = cc >> 1;
      float embed = (float)(e + 1) * (6.283185307179586f / 8.000001f);
      float dt = powf(10000.0f, (float)m * (1.0f / 48.0f));
      float ang = embed / dt;
      rp[jj] = (cc & 1) ? cosf(ang) : sinf(ang);
    }
    *(float4*)(pos + p0) = r;
    return;
  } else return;
  const float* s = src + off * 4;
  short4 r;
  r.x = f2bf(s[0]); r.y = f2bf(s[1]); r.z = f2bf(s[2]); r.w = f2bf(s[3]);
  *(short4*)(dst + off * 4) = r;
}

// ---- QKV pre-kernel: one block per (b,t). Q,K row-major [hw][ch]; V transposed [ch][hw].
// Grid swizzled with the SAME XCD mapping as fused_all (r4-verified: FETCH 186->78MB).
__global__ __launch_bounds__(256) void qkv_kernel(
    const float* __restrict__ x, const float* __restrict__ pos,
    const short* __restrict__ Wqkv_bf,
    short* __restrict__ Qb, short* __restrict__ Kb, short* __restrict__ Vtb) {
  __shared__ short XP[64 * 200];
  int bid = blockIdx.x;
  int xcd = bid & 7, idx = bid >> 3;   // 96 blocks per XCD
  int bq = idx / TT;
  int b = xcd * 16 + bq, t = idx - bq * TT;
  int tid = threadIdx.x, w = tid >> 6, lane = tid & 63;
  int l15 = lane & 15, quad = lane >> 4;
  const float* xrow = x + (size_t)(b * (TT * 64) + t * 64) * DIM;
  for (int c = tid; c < 64 * 24; c += 256) {
    int row = c / 24, col8 = (c - (c / 24) * 24) * 8;
    const float* xs = xrow + row * DIM + col8;
    const float* pp = pos + row * DIM + col8;
    v8s r8;
#pragma unroll
    for (int jj = 0; jj < 8; jj++) r8[jj] = f2bf(xs[jj] + pp[jj]);
    *(v8s*)(XP + row * 200 + col8) = r8;
  }
  __syncthreads();
  const v4f vzero = {0.f, 0.f, 0.f, 0.f};
  size_t obase = (size_t)(b * TT + t) * 64 * DIM;
#pragma unroll
  for (int cti = 0; cti < 9; cti++) {
    int r0 = w * 144 + cti * 16;
    v4f acc[4] = {vzero, vzero, vzero, vzero};
#pragma unroll
    for (int ks = 0; ks < 6; ks++) {
      v8s a = *(const v8s*)(Wqkv_bf + (size_t)(r0 + l15) * 192 + ks * 32 + quad * 8);
#pragma unroll
      for (int nt = 0; nt < 4; nt++) {
        v8s bb = *(const v8s*)(XP + (nt * 16 + l15) * 200 + ks * 32 + quad * 8);
        acc[nt] = __builtin_amdgcn_mfma_f32_16x16x32_bf16(a, bb, acc[nt], 0, 0, 0);
      }
    }
    int R = r0 + quad * 4;
#pragma unroll
    for (int nt = 0; nt < 4; nt++) {
      int hw = nt * 16 + l15;
      if (R < 192) {
        short4 s;
        s.x = f2bf(acc[nt][0] * SCALE); s.y = f2bf(acc[nt][1] * SCALE);
        s.z = f2bf(acc[nt][2] * SCALE); s.w = f2bf(acc[nt][3] * SCALE);
        *(short4*)(Qb + obase + (size_t)hw * 192 + R) = s;
      } else if (R < 384) {
        short4 s;
        s.x = f2bf(acc[nt][0]); s.y = f2bf(acc[nt][1]);
        s.z = f2bf(acc[nt][2]); s.w = f2bf(acc[nt][3]);
        *(short4*)(Kb + obase + (size_t)hw * 192 + (R - 192)) = s;
      } else {
#pragma unroll
        for (int r = 0; r < 4; r++)
          Vtb[obase + (size_t)(R - 384 + r) * 64 + hw] = f2bf(acc[nt][r]);
      }
    }
  }
}

// ---- main fused kernel: one block per (i,b), 512 threads (8 waves).
// r1 compute body (y1x hoist + Pl transpose, best at 453us) + 4 barriers/j:
//   A: o ready | G1+LNp | B: LN | y1n | C: G2 | gelu->HB | D: G3(HB) ; attn(j+1)->SP
// sched_barrier(0) between G3 and attn stops the compiler merging their live
// ranges (r6's merge without it spilled ~1.6GB of scratch: FETCH 78->1324MB).
// Wave-drift overlap across the D..A region needs no intra-wave interleave.
__global__ __launch_bounds__(512, 4) void fused_all(
    const float* __restrict__ x,
    const short* __restrict__ Qb, const short* __restrict__ Kb,
    const short* __restrict__ Vtb,
    const short* __restrict__ Wproj_bf, const short* __restrict__ W1_bf,
    const short* __restrict__ W2_bf,
    const float* __restrict__ bproj, const float* __restrict__ gamma,
    const float* __restrict__ beta, const float* __restrict__ b1,
    const float* __restrict__ b2,
    float* __restrict__ out) {
  __shared__ short SP[64 * 200];     // Xi staging / o / y1n; f32 acc staging in epilogue
  __shared__ short HB[64 * 200];     // gelu output h
  __shared__ short Pl[8][16 * 72];   // per-wave P: [q][hw_k]
  __shared__ float LNp[64][4][2];    // LN partials: [hw][wc][s1,s2]

  int bid = blockIdx.x;
  int xcd = bid & 7, idx6 = bid >> 3;
  int bq = idx6 / TT;
  int b = xcd * 16 + bq, i = idx6 - bq * TT;

  int tid = threadIdx.x, w = tid >> 6, lane = tid & 63;
  int l15 = lane & 15, quad = lane >> 4;
  int wc = w & 3, wh = w >> 2;
  int cb = wc * 48;
  const v4f vzero = {0.f, 0.f, 0.f, 0.f};

  // ---- stage Xi as bf16 into SP (transient) ----
  const float* xi = x + (size_t)(i * NB + b) * 64 * DIM;
  for (int c = tid; c < 64 * 24; c += 512) {
    int row = c / 24, col8 = (c - (c / 24) * 24) * 8;
    const float* xs = xi + row * DIM + col8;
    v8s r8;
#pragma unroll
    for (int jj = 0; jj < 8; jj++) r8[jj] = f2bf(xs[jj]);
    *(v8s*)(SP + row * 200 + col8) = r8;
  }

  // ---- hoist Q fragments (j-invariant) ----
  const short* Qi = Qb + (size_t)(b * TT + i) * 64 * DIM;
  v8s qa[3];
#pragma unroll
  for (int hh = 0; hh < 3; hh++)
    qa[hh] = *(const v8s*)(Qi + (size_t)(wc * 16 + l15) * 192 + (wh * 3 + hh) * 32 + quad * 8);

  v4f acc[3][2];
#pragma unroll
  for (int cti = 0; cti < 3; cti++)
#pragma unroll
    for (int nt = 0; nt < 2; nt++) acc[cti][nt] = vzero;

  __syncthreads();                   // Xi staged

  // ---- y1x = Wproj[:,192:384] . Xi^T (j-invariant, registers) ----
  v4f y1x[3][2];
#pragma unroll
  for (int cti = 0; cti < 3; cti++)
#pragma unroll
    for (int nt = 0; nt < 2; nt++) y1x[cti][nt] = vzero;
#pragma unroll
  for (int ks = 0; ks < 6; ks++) {
    v8s bxi[2];
#pragma unroll
    for (int nt = 0; nt < 2; nt++)
      bxi[nt] = *(const v8s*)(SP + (wh * 32 + nt * 16 + l15) * 200 + ks * 32 + quad * 8);
#pragma unroll
    for (int cti = 0; cti < 3; cti++) {
      v8s a = *(const v8s*)(Wproj_bf + (size_t)(cb + cti * 16 + l15) * 384 + 192 + ks * 32 + quad * 8);
#pragma unroll
      for (int nt = 0; nt < 2; nt++)
        y1x[cti][nt] = __builtin_amdgcn_mfma_f32_16x16x32_bf16(a, bxi[nt], y1x[cti][nt], 0, 0, 0);
    }
  }
  __syncthreads();                   // y1x SP reads done; SP free for o

  // ---- attention for one (Kj, Vj): writes o into SP (r1's Pl-transpose path) ----
  auto attn = [&](const short* Kj, const short* Vj) {
#pragma unroll
    for (int hh = 0; hh < 3; hh++) {
      int h = wh * 3 + hh;
      v4f S[4];
#pragma unroll
      for (int cta = 0; cta < 4; cta++) {
        v8s akq = *(const v8s*)(Kj + (size_t)(cta * 16 + l15) * 192 + h * 32 + quad * 8);
        S[cta] = __builtin_amdgcn_mfma_f32_16x16x32_bf16(akq, qa[hh], vzero, 0, 0, 0);
      }
      float mx = -1e30f;
#pragma unroll
      for (int cta = 0; cta < 4; cta++)
#pragma unroll
        for (int r = 0; r < 4; r++) mx = fmaxf(mx, S[cta][r]);
      mx = fmaxf(mx, __shfl_xor(mx, 16, 64));
      mx = fmaxf(mx, __shfl_xor(mx, 32, 64));
      float sum = 0.f;
#pragma unroll
      for (int cta = 0; cta < 4; cta++)
#pragma unroll
        for (int r = 0; r < 4; r++) {
          float e = __expf(S[cta][r] - mx);
          S[cta][r] = e; sum += e;
        }
      sum += __shfl_xor(sum, 16, 64);
      sum += __shfl_xor(sum, 32, 64);
      float inv = 1.0f / sum;
#pragma unroll
      for (int cta = 0; cta < 4; cta++) {
        short4 s;
        s.x = f2bf(S[cta][0] * inv); s.y = f2bf(S[cta][1] * inv);
        s.z = f2bf(S[cta][2] * inv); s.w = f2bf(S[cta][3] * inv);
        *(short4*)(&Pl[w][l15 * 72 + cta * 16 + quad * 4]) = s;
      }
      fence();
      v8s bp0 = *(const v8s*)(&Pl[w][l15 * 72 + quad * 8]);
      v8s bp1 = *(const v8s*)(&Pl[w][l15 * 72 + 32 + quad * 8]);
#pragma unroll
      for (int ct2 = 0; ct2 < 2; ct2++) {
        v8s av0 = *(const v8s*)(Vj + (size_t)(h * 32 + ct2 * 16 + l15) * 64 + quad * 8);
        v8s av1 = *(const v8s*)(Vj + (size_t)(h * 32 + ct2 * 16 + l15) * 64 + 32 + quad * 8);
        v4f o = __builtin_amdgcn_mfma_f32_16x16x32_bf16(av0, bp0, vzero, 0, 0, 0);
        o = __builtin_amdgcn_mfma_f32_16x16x32_bf16(av1, bp1, o, 0, 0, 0);
        short4 s;
        s.x = f2bf(o[0]); s.y = f2bf(o[1]); s.z = f2bf(o[2]); s.w = f2bf(o[3]);
        *(short4*)(&SP[(wc * 16 + l15) * 200 + h * 32 + ct2 * 16 + quad * 4]) = s;
      }
      fence();
    }
  };

  attn(Kb + (size_t)(b * TT) * 64 * DIM,
       Vtb + (size_t)(b * TT) * 64 * DIM);   // j = 0 prologue

  for (int j = 0; j < TT; j++) {
    __syncthreads();               // A: o_j ready; G3(j-1) HB reads done

    // ---- G1: y1 = y1x + Wproj[:,0:192] . o^T ----
    v4f y1[3][2];
#pragma unroll
    for (int cti = 0; cti < 3; cti++)
#pragma unroll
      for (int nt = 0; nt < 2; nt++) y1[cti][nt] = y1x[cti][nt];
#pragma unroll
    for (int ks = 0; ks < 6; ks++) {
      v8s bo[2];
#pragma unroll
      for (int nt = 0; nt < 2; nt++)
        bo[nt] = *(const v8s*)(SP + (wh * 32 + nt * 16 + l15) * 200 + ks * 32 + quad * 8);
#pragma unroll
      for (int cti = 0; cti < 3; cti++) {
        v8s a = *(const v8s*)(Wproj_bf + (size_t)(cb + cti * 16 + l15) * 384 + ks * 32 + quad * 8);
#pragma unroll
        for (int nt = 0; nt < 2; nt++)
          y1[cti][nt] = __builtin_amdgcn_mfma_f32_16x16x32_bf16(a, bo[nt], y1[cti][nt], 0, 0, 0);
      }
    }
#pragma unroll
    for (int cti = 0; cti < 3; cti++) {
      float4 bp4 = *(const float4*)(bproj + cb + cti * 16 + quad * 4);
#pragma unroll
      for (int nt = 0; nt < 2; nt++) {
        y1[cti][nt][0] += bp4.x; y1[cti][nt][1] += bp4.y;
        y1[cti][nt][2] += bp4.z; y1[cti][nt][3] += bp4.w;
      }
    }
#pragma unroll
    for (int nt = 0; nt < 2; nt++) {
      float s1 = 0.f, s2 = 0.f;
#pragma unroll
      for (int cti = 0; cti < 3; cti++)
#pragma unroll
        for (int r = 0; r < 4; r++) { float v = y1[cti][nt][r]; s1 += v; s2 += v * v; }
      s1 += __shfl_xor(s1, 16, 64); s2 += __shfl_xor(s2, 16, 64);
      s1 += __shfl_xor(s1, 32, 64); s2 += __shfl_xor(s2, 32, 64);
      if (quad == 0) {
        LNp[wh * 32 + nt * 16 + l15][wc][0] = s1;
        LNp[wh * 32 + nt * 16 + l15][wc][1] = s2;
      }
    }
    __syncthreads();               // B: partials visible; G1 SP reads done
    float mu[2], rs[2];
#pragma unroll
    for (int nt = 0; nt < 2; nt++) {
      int row = wh * 32 + nt * 16 + l15;
      float s1 = 0.f, s2 = 0.f;
#pragma unroll
      for (int ww = 0; ww < 4; ww++) { s1 += LNp[row][ww][0]; s2 += LNp[row][ww][1]; }
      float m = s1 * (1.0f / 192.0f);
      mu[nt] = m; rs[nt] = rsqrtf(s2 * (1.0f / 192.0f) - m * m + 1e-5f);
    }
#pragma unroll
    for (int cti = 0; cti < 3; cti++) {
      float4 g4 = *(const float4*)(gamma + cb + cti * 16 + quad * 4);
      float4 be4 = *(const float4*)(beta + cb + cti * 16 + quad * 4);
#pragma unroll
      for (int nt = 0; nt < 2; nt++) {
        short4 s;
        s.x = f2bf((y1[cti][nt][0] - mu[nt]) * rs[nt] * g4.x + be4.x);
        s.y = f2bf((y1[cti][nt][1] - mu[nt]) * rs[nt] * g4.y + be4.y);
        s.z = f2bf((y1[cti][nt][2] - mu[nt]) * rs[nt] * g4.z + be4.z);
        s.w = f2bf((y1[cti][nt][3] - mu[nt]) * rs[nt] * g4.w + be4.w);
        *(short4*)(&SP[(wh * 32 + nt * 16 + l15) * 200 + cb + cti * 16 + quad * 4]) = s;
      }
    }
    __syncthreads();               // C: y1n ready

    // ---- G2: y2 = W1 . y1n^T ; gelu -> HB ----
    v4f y2[3][2];
#pragma unroll
    for (int cti = 0; cti < 3; cti++)
#pragma unroll
      for (int nt = 0; nt < 2; nt++) y2[cti][nt] = vzero;
#pragma unroll
    for (int ks = 0; ks < 6; ks++) {
      v8s bh[2];
#pragma unroll
      for (int nt = 0; nt < 2; nt++)
        bh[nt] = *(const v8s*)(SP + (wh * 32 + nt * 16 + l15) * 200 + ks * 32 + quad * 8);
#pragma unroll
      for (int cti = 0; cti < 3; cti++) {
        v8s a = *(const v8s*)(W1_bf + (size_t)(cb + cti * 16 + l15) * 192 + ks * 32 + quad * 8);
#pragma unroll
        for (int nt = 0; nt < 2; nt++)
          y2[cti][nt] = __builtin_amdgcn_mfma_f32_16x16x32_bf16(a, bh[nt], y2[cti][nt], 0, 0, 0);
      }
    }
#pragma unroll
    for (int cti = 0; cti < 3; cti++) {
      float4 b14 = *(const float4*)(b1 + cb + cti * 16 + quad * 4);
#pragma unroll
      for (int nt = 0; nt < 2; nt++) {
        float vv[4] = {y2[cti][nt][0] + b14.x, y2[cti][nt][1] + b14.y,
                       y2[cti][nt][2] + b14.z, y2[cti][nt][3] + b14.w};
        short sv[4];
#pragma unroll
        for (int r = 0; r < 4; r++) {
          float v = vv[r];
          float t = 0.79788456080286536f * (v + 0.044715f * v * v * v);
          float e = __expf(2.0f * t);
          float th = 1.0f - 2.0f / (e + 1.0f);
          sv[r] = f2bf(0.5f * v * (1.0f + th));
        }
        short4 s;
        s.x = sv[0]; s.y = sv[1]; s.z = sv[2]; s.w = sv[3];
        *(short4*)(&HB[(wh * 32 + nt * 16 + l15) * 200 + cb + cti * 16 + quad * 4]) = s;
      }
    }
    __syncthreads();               // D: h ready; G2 SP reads done -> SP free

    // ---- G3: acc += W2 . h^T (from HB) ----
#pragma unroll
    for (int ks = 0; ks < 6; ks++) {
      v8s bh[2];
#pragma unroll
      for (int nt = 0; nt < 2; nt++)
        bh[nt] = *(const v8s*)(HB + (wh * 32 + nt * 16 + l15) * 200 + ks * 32 + quad * 8);
#pragma unroll
      for (int cti = 0; cti < 3; cti++) {
        v8s a = *(const v8s*)(W2_bf + (size_t)(cb + cti * 16 + l15) * 192 + ks * 32 + quad * 8);
#pragma unroll
        for (int nt = 0; nt < 2; nt++)
          acc[cti][nt] = __builtin_amdgcn_mfma_f32_16x16x32_bf16(a, bh[nt], acc[cti][nt], 0, 0, 0);
      }
    }
    // Hard scheduling wall: keep G3's and attn's live ranges disjoint so the
    // register allocator never holds both phases' temps at once (r6 lesson).
    __builtin_amdgcn_sched_barrier(0);
    if (j < TT - 1) {
      attn(Kb + (size_t)(b * TT + j + 1) * 64 * DIM,
           Vtb + (size_t)(b * TT + j + 1) * 64 * DIM);
    }
  }

  // ---- epilogue: stage acc/6 to LDS (f32), write full contiguous rows ----
  float* SPf = (float*)SP;
#pragma unroll
  for (int pass = 0; pass < 2; pass++) {
    __syncthreads();
    if (wh == pass) {
#pragma unroll
      for (int cti = 0; cti < 3; cti++)
#pragma unroll
        for (int nt = 0; nt < 2; nt++) {
          float4 o4;
          o4.x = acc[cti][nt][0] * (1.0f / 6.0f);
          o4.y = acc[cti][nt][1] * (1.0f / 6.0f);
          o4.z = acc[cti][nt][2] * (1.0f / 6.0f);
          o4.w = acc[cti][nt][3] * (1.0f / 6.0f);
          *(float4*)(&SPf[(nt * 16 + l15) * 196 + cb + cti * 16 + quad * 4]) = o4;
        }
    }
    __syncthreads();
    for (int c = tid; c < 1536; c += 512) {
      int r32 = c / 48, col4 = (c - r32 * 48) * 4;
      int row = pass * 32 + r32;
      size_t nrow = (size_t)b * 384 + (size_t)i * 64 + row;
      float4 xv = *(const float4*)(x + nrow * DIM + col4);
      float4 b24 = *(const float4*)(b2 + col4);
      float4 av = *(const float4*)(&SPf[r32 * 196 + col4]);
      float4 o4;
      o4.x = xv.x + av.x + b24.x;
      o4.y = xv.y + av.y + b24.y;
      o4.z = xv.z + av.z + b24.z;
      o4.w = xv.w + av.w + b24.w;
      *(float4*)(out + nrow * 384 + col4) = xv;             // x half bit-exact
      *(float4*)(out + nrow * 384 + 192 + col4) = o4;
    }
  }
}

extern "C" void kernel_launch(void* const* d_in, const int* in_sizes, int n_in,
                              void* d_out, int out_size, void* d_ws, size_t ws_size,
                              hipStream_t stream) {
  (void)in_sizes; (void)n_in; (void)out_size; (void)ws_size;
  const float* x     = (const float*)d_in[0];
  const float* Wqkv  = (const float*)d_in[1];
  const float* Wproj = (const float*)d_in[2];
  const float* bproj = (const float*)d_in[3];
  const float* gamma = (const float*)d_in[4];
  const float* beta  = (const float*)d_in[5];
  const float* W1    = (const float*)d_in[6];
  const float* b1    = (const float*)d_in[7];
  const float* W2    = (const float*)d_in[8];
  const float* b2    = (const float*)d_in[9];
  float* out = (float*)d_out;

  // workspace: weights bf16 + pos f32 + Q/K/Vt bf16
  short* Wqkv_bf  = (short*)d_ws;                 // 576*192
  short* Wproj_bf = Wqkv_bf + 110592;             // 192*384
  short* W1_bf    = Wproj_bf + 73728;             // 192*192
  short* W2_bf    = W1_bf + 36864;                // 192*192
  float* pos_f    = (float*)(W2_bf + 36864);      // 64*192 f32
  short* Qb       = (short*)(pos_f + 12288);      // [b][t][hw][ch]
  short* Kb       = Qb + 9437184;                 // [b][t][hw][ch]
  short* Vtb      = Kb + 9437184;                 // [b][t][ch][hw]

  prep_kernel<<<dim3(264), dim3(256), 0, stream>>>(
      Wqkv, Wproj, W1, W2, Wqkv_bf, Wproj_bf, W1_bf, W2_bf, pos_f);
  qkv_kernel<<<dim3(TT * NB), dim3(256), 0, stream>>>(x, pos_f, Wqkv_bf, Qb, Kb, Vtb);
  fused_all<<<dim3(TT * NB), dim3(512), 0, stream>>>(
      x, Qb, Kb, Vtb, Wproj_bf, W1_bf, W2_bf, bproj, gamma, beta, b1, b2, out);
}

// Round 8
// 569.197 us; speedup vs baseline: 1.6348x; 1.6268x over previous
//
#include <hip/hip_runtime.h>
#include <cmath>

#define TT   6
#define NB   128
#define DIM  192
#define SCALE 0.17677669529663687f

typedef __attribute__((ext_vector_type(8))) short v8s;
typedef __attribute__((ext_vector_type(4))) float v4f;

__device__ __forceinline__ short f2bf(float f) {
  union { float f; unsigned u; } v; v.f = f;
  unsigned r = v.u + 0x7fffu + ((v.u >> 16) & 1u);
  return (short)(r >> 16);
}
__device__ __forceinline__ void fence() {
  __asm__ volatile("s_waitcnt lgkmcnt(0)" ::: "memory");
}

// ---- fused prep: bf16 weight conversion + sine position table, one launch ----
__global__ void prep_kernel(const float* __restrict__ Wqkv, const float* __restrict__ Wproj,
                            const float* __restrict__ W1, const float* __restrict__ W2,
                            short* __restrict__ dWqkv, short* __restrict__ dWproj,
                            short* __restrict__ dW1, short* __restrict__ dW2,
                            float* __restrict__ pos) {
  int idx = blockIdx.x * 256 + threadIdx.x;
  const float* src = nullptr; short* dst = nullptr; int off = 0;
  if (idx < 27648)      { src = Wqkv;  dst = dWqkv;  off = idx; }
  else if (idx < 46080) { src = Wproj; dst = dWproj; off = idx - 27648; }
  else if (idx < 55296) { src = W1;    dst = dW1;    off = idx - 46080; }
  else if (idx < 64512) { src = W2;    dst = dW2;    off = idx - 55296; }
  else if (idx < 67584) {
    int p0 = (idx - 64512) * 4;
    float4 r;
    float* rp = (float*)&r;
#pragma unroll
    for (int jj = 0; jj < 4; jj++) {
      int p = p0 + jj;
      int row = p / 192, c = p - row * 192;
      int e  = (c < 96) ? (row >> 3) : (row & 7);
      int cc = (c < 96) ? c : c - 96;
      int m = cc >> 1;
      float embed = (float)(e + 1) * (6.283185307179586f / 8.000001f);
      float dt = powf(10000.0f, (float)m * (1.0f / 48.0f));
      float ang = embed / dt;
      rp[jj] = (cc & 1) ? cosf(ang) : sinf(ang);
    }
    *(float4*)(pos + p0) = r;
    return;
  } else return;
  const float* s = src + off * 4;
  short4 r;
  r.x = f2bf(s[0]); r.y = f2bf(s[1]); r.z = f2bf(s[2]); r.w = f2bf(s[3]);
  *(short4*)(dst + off * 4) = r;
}

// ---- QKV pre-kernel: one block per (b,t). Q,K row-major [hw][ch]; V transposed [ch][hw].
// Grid swizzled with the SAME XCD mapping as fused_all (r4-verified: FETCH 186->78MB).
__global__ __launch_bounds__(256) void qkv_kernel(
    const float* __restrict__ x, const float* __restrict__ pos,
    const short* __restrict__ Wqkv_bf,
    short* __restrict__ Qb, short* __restrict__ Kb, short* __restrict__ Vtb) {
  __shared__ short XP[64 * 200];
  int bid = blockIdx.x;
  int xcd = bid & 7, idx = bid >> 3;   // 96 blocks per XCD
  int bq = idx / TT;
  int b = xcd * 16 + bq, t = idx - bq * TT;
  int tid = threadIdx.x, w = tid >> 6, lane = tid & 63;
  int l15 = lane & 15, quad = lane >> 4;
  const float* xrow = x + (size_t)(b * (TT * 64) + t * 64) * DIM;
  for (int c = tid; c < 64 * 24; c += 256) {
    int row = c / 24, col8 = (c - (c / 24) * 24) * 8;
    const float* xs = xrow + row * DIM + col8;
    const float* pp = pos + row * DIM + col8;
    v8s r8;
#pragma unroll
    for (int jj = 0; jj < 8; jj++) r8[jj] = f2bf(xs[jj] + pp[jj]);
    *(v8s*)(XP + row * 200 + col8) = r8;
  }
  __syncthreads();
  const v4f vzero = {0.f, 0.f, 0.f, 0.f};
  size_t obase = (size_t)(b * TT + t) * 64 * DIM;
#pragma unroll
  for (int cti = 0; cti < 9; cti++) {
    int r0 = w * 144 + cti * 16;
    v4f acc[4] = {vzero, vzero, vzero, vzero};
#pragma unroll
    for (int ks = 0; ks < 6; ks++) {
      v8s a = *(const v8s*)(Wqkv_bf + (size_t)(r0 + l15) * 192 + ks * 32 + quad * 8);
#pragma unroll
      for (int nt = 0; nt < 4; nt++) {
        v8s bb = *(const v8s*)(XP + (nt * 16 + l15) * 200 + ks * 32 + quad * 8);
        acc[nt] = __builtin_amdgcn_mfma_f32_16x16x32_bf16(a, bb, acc[nt], 0, 0, 0);
      }
    }
    int R = r0 + quad * 4;
#pragma unroll
    for (int nt = 0; nt < 4; nt++) {
      int hw = nt * 16 + l15;
      if (R < 192) {
        short4 s;
        s.x = f2bf(acc[nt][0] * SCALE); s.y = f2bf(acc[nt][1] * SCALE);
        s.z = f2bf(acc[nt][2] * SCALE); s.w = f2bf(acc[nt][3] * SCALE);
        *(short4*)(Qb + obase + (size_t)hw * 192 + R) = s;
      } else if (R < 384) {
        short4 s;
        s.x = f2bf(acc[nt][0]); s.y = f2bf(acc[nt][1]);
        s.z = f2bf(acc[nt][2]); s.w = f2bf(acc[nt][3]);
        *(short4*)(Kb + obase + (size_t)hw * 192 + (R - 192)) = s;
      } else {
#pragma unroll
        for (int r = 0; r < 4; r++)
          Vtb[obase + (size_t)(R - 384 + r) * 64 + hw] = f2bf(acc[nt][r]);
      }
    }
  }
}

// ---- main fused kernel: one block per (i,b,half), 256 threads (4 waves), 32 hw rows.
// Per-wave tiles are identical to the verified r1 body (3cti x 2nt GEMM tiles; 16 q-rows
// x 3 heads attention); only the wave->work map changed (wc=w; qt=w&1, hg=w>>1).
// Rationale: r1 was latency/barrier-bound with 2x 8-wave barrier domains per CU.
// Halving the block gives 4 independent 4-wave domains per CU (LDS 35.8KB -> 4 blocks)
// so one block's barrier/L3 stall is hidden by three others.
// 5 barriers/j (gelu->HB removes one); attn stays alone between barriers (r6/r7's
// tail-merge caused a ~1.6GB scratch-spill blowup -- do not merge).
__global__ __launch_bounds__(256, 4) void fused_all(
    const float* __restrict__ x,
    const short* __restrict__ Qb, const short* __restrict__ Kb,
    const short* __restrict__ Vtb,
    const short* __restrict__ Wproj_bf, const short* __restrict__ W1_bf,
    const short* __restrict__ W2_bf,
    const float* __restrict__ bproj, const float* __restrict__ gamma,
    const float* __restrict__ beta, const float* __restrict__ b1,
    const float* __restrict__ b2,
    float* __restrict__ out) {
  __shared__ short SP[32 * 200];     // Xi staging / o / y1n; f32 acc staging in epilogue
  __shared__ short HB[32 * 200];     // gelu output h
  __shared__ short Pl[4][16 * 72];   // per-wave P: [q][hw_k]
  __shared__ float LNp[32][4][2];    // LN partials: [row][wc][s1,s2]

  // XCD swizzle: 12 blocks (6 i x 2 half) sharing b land on one XCD
  int bid = blockIdx.x;
  int xcd = bid & 7, idx = bid >> 3;     // 192 per XCD
  int bq = idx / 12;
  int rem = idx - bq * 12;
  int i = rem >> 1, half = rem & 1;
  int b = xcd * 16 + bq;

  int tid = threadIdx.x, w = tid >> 6, lane = tid & 63;
  int l15 = lane & 15, quad = lane >> 4;
  int wc = w;                        // GEMM channel slice
  int qt = w & 1, hg = w >> 1;       // attention: q-tile, head-group
  int cb = wc * 48;
  const v4f vzero = {0.f, 0.f, 0.f, 0.f};

  // ---- stage Xi (x.view rows, this half) as bf16 into SP ----
  const float* xi = x + (size_t)((i * NB + b) * 64 + half * 32) * DIM;
  for (int c = tid; c < 32 * 24; c += 256) {
    int row = c / 24, col8 = (c - (c / 24) * 24) * 8;
    const float* xs = xi + row * DIM + col8;
    v8s r8;
#pragma unroll
    for (int jj = 0; jj < 8; jj++) r8[jj] = f2bf(xs[jj]);
    *(v8s*)(SP + row * 200 + col8) = r8;
  }

  // ---- hoist Q fragments (j-invariant): wave's 16 q-rows x its 3 heads ----
  const short* Qi = Qb + (size_t)(b * TT + i) * 64 * DIM;
  v8s qa[3];
#pragma unroll
  for (int hh = 0; hh < 3; hh++)
    qa[hh] = *(const v8s*)(Qi + (size_t)(half * 32 + qt * 16 + l15) * 192 + (hg * 3 + hh) * 32 + quad * 8);

  v4f acc[3][2];
#pragma unroll
  for (int cti = 0; cti < 3; cti++)
#pragma unroll
    for (int nt = 0; nt < 2; nt++) acc[cti][nt] = vzero;

  __syncthreads();                   // Xi staged

  // ---- y1x = Wproj[:,192:384] . Xi^T (j-invariant, registers) ----
  v4f y1x[3][2];
#pragma unroll
  for (int cti = 0; cti < 3; cti++)
#pragma unroll
    for (int nt = 0; nt < 2; nt++) y1x[cti][nt] = vzero;
#pragma unroll
  for (int ks = 0; ks < 6; ks++) {
    v8s bxi[2];
#pragma unroll
    for (int nt = 0; nt < 2; nt++)
      bxi[nt] = *(const v8s*)(SP + (nt * 16 + l15) * 200 + ks * 32 + quad * 8);
#pragma unroll
    for (int cti = 0; cti < 3; cti++) {
      v8s a = *(const v8s*)(Wproj_bf + (size_t)(cb + cti * 16 + l15) * 384 + 192 + ks * 32 + quad * 8);
#pragma unroll
      for (int nt = 0; nt < 2; nt++)
        y1x[cti][nt] = __builtin_amdgcn_mfma_f32_16x16x32_bf16(a, bxi[nt], y1x[cti][nt], 0, 0, 0);
    }
  }

  for (int j = 0; j < TT; j++) {
    __syncthreads();               // A: j=0: y1x SP reads done; j>0: G2 SP reads + G3 HB reads done
    {
      const short* Kj = Kb + (size_t)(b * TT + j) * 64 * DIM;
      const short* Vj = Vtb + (size_t)(b * TT + j) * 64 * DIM;
#pragma unroll
      for (int hh = 0; hh < 3; hh++) {
        int h = hg * 3 + hh;
        v4f S[4];
#pragma unroll
        for (int cta = 0; cta < 4; cta++) {
          v8s akq = *(const v8s*)(Kj + (size_t)(cta * 16 + l15) * 192 + h * 32 + quad * 8);
          S[cta] = __builtin_amdgcn_mfma_f32_16x16x32_bf16(akq, qa[hh], vzero, 0, 0, 0);
        }
        float mx = -1e30f;
#pragma unroll
        for (int cta = 0; cta < 4; cta++)
#pragma unroll
          for (int r = 0; r < 4; r++) mx = fmaxf(mx, S[cta][r]);
        mx = fmaxf(mx, __shfl_xor(mx, 16, 64));
        mx = fmaxf(mx, __shfl_xor(mx, 32, 64));
        float sum = 0.f;
#pragma unroll
        for (int cta = 0; cta < 4; cta++)
#pragma unroll
          for (int r = 0; r < 4; r++) {
            float e = __expf(S[cta][r] - mx);
            S[cta][r] = e; sum += e;
          }
        sum += __shfl_xor(sum, 16, 64);
        sum += __shfl_xor(sum, 32, 64);
        float inv = 1.0f / sum;
#pragma unroll
        for (int cta = 0; cta < 4; cta++) {
          short4 s;
          s.x = f2bf(S[cta][0] * inv); s.y = f2bf(S[cta][1] * inv);
          s.z = f2bf(S[cta][2] * inv); s.w = f2bf(S[cta][3] * inv);
          *(short4*)(&Pl[w][l15 * 72 + cta * 16 + quad * 4]) = s;
        }
        fence();
        v8s bp0 = *(const v8s*)(&Pl[w][l15 * 72 + quad * 8]);
        v8s bp1 = *(const v8s*)(&Pl[w][l15 * 72 + 32 + quad * 8]);
#pragma unroll
        for (int ct2 = 0; ct2 < 2; ct2++) {
          v8s av0 = *(const v8s*)(Vj + (size_t)(h * 32 + ct2 * 16 + l15) * 64 + quad * 8);
          v8s av1 = *(const v8s*)(Vj + (size_t)(h * 32 + ct2 * 16 + l15) * 64 + 32 + quad * 8);
          v4f o = __builtin_amdgcn_mfma_f32_16x16x32_bf16(av0, bp0, vzero, 0, 0, 0);
          o = __builtin_amdgcn_mfma_f32_16x16x32_bf16(av1, bp1, o, 0, 0, 0);
          short4 s;
          s.x = f2bf(o[0]); s.y = f2bf(o[1]); s.z = f2bf(o[2]); s.w = f2bf(o[3]);
          *(short4*)(&SP[(qt * 16 + l15) * 200 + h * 32 + ct2 * 16 + quad * 4]) = s;
        }
        fence();
      }
    }
    __syncthreads();               // B: o ready

    // ---- G1: y1 = y1x + Wproj[:,0:192] . o^T ----
    v4f y1[3][2];
#pragma unroll
    for (int cti = 0; cti < 3; cti++)
#pragma unroll
      for (int nt = 0; nt < 2; nt++) y1[cti][nt] = y1x[cti][nt];
#pragma unroll
    for (int ks = 0; ks < 6; ks++) {
      v8s bo[2];
#pragma unroll
      for (int nt = 0; nt < 2; nt++)
        bo[nt] = *(const v8s*)(SP + (nt * 16 + l15) * 200 + ks * 32 + quad * 8);
#pragma unroll
      for (int cti = 0; cti < 3; cti++) {
        v8s a = *(const v8s*)(Wproj_bf + (size_t)(cb + cti * 16 + l15) * 384 + ks * 32 + quad * 8);
#pragma unroll
        for (int nt = 0; nt < 2; nt++)
          y1[cti][nt] = __builtin_amdgcn_mfma_f32_16x16x32_bf16(a, bo[nt], y1[cti][nt], 0, 0, 0);
      }
    }
#pragma unroll
    for (int cti = 0; cti < 3; cti++) {
      float4 bp4 = *(const float4*)(bproj + cb + cti * 16 + quad * 4);
#pragma unroll
      for (int nt = 0; nt < 2; nt++) {
        y1[cti][nt][0] += bp4.x; y1[cti][nt][1] += bp4.y;
        y1[cti][nt][2] += bp4.z; y1[cti][nt][3] += bp4.w;
      }
    }
#pragma unroll
    for (int nt = 0; nt < 2; nt++) {
      float s1 = 0.f, s2 = 0.f;
#pragma unroll
      for (int cti = 0; cti < 3; cti++)
#pragma unroll
        for (int r = 0; r < 4; r++) { float v = y1[cti][nt][r]; s1 += v; s2 += v * v; }
      s1 += __shfl_xor(s1, 16, 64); s2 += __shfl_xor(s2, 16, 64);
      s1 += __shfl_xor(s1, 32, 64); s2 += __shfl_xor(s2, 32, 64);
      if (quad == 0) {
        LNp[nt * 16 + l15][wc][0] = s1;
        LNp[nt * 16 + l15][wc][1] = s2;
      }
    }
    __syncthreads();               // C: partials visible; G1 SP reads done
    float mu[2], rs[2];
#pragma unroll
    for (int nt = 0; nt < 2; nt++) {
      int row = nt * 16 + l15;
      float s1 = 0.f, s2 = 0.f;
#pragma unroll
      for (int ww = 0; ww < 4; ww++) { s1 += LNp[row][ww][0]; s2 += LNp[row][ww][1]; }
      float m = s1 * (1.0f / 192.0f);
      mu[nt] = m; rs[nt] = rsqrtf(s2 * (1.0f / 192.0f) - m * m + 1e-5f);
    }
#pragma unroll
    for (int cti = 0; cti < 3; cti++) {
      float4 g4 = *(const float4*)(gamma + cb + cti * 16 + quad * 4);
      float4 be4 = *(const float4*)(beta + cb + cti * 16 + quad * 4);
#pragma unroll
      for (int nt = 0; nt < 2; nt++) {
        short4 s;
        s.x = f2bf((y1[cti][nt][0] - mu[nt]) * rs[nt] * g4.x + be4.x);
        s.y = f2bf((y1[cti][nt][1] - mu[nt]) * rs[nt] * g4.y + be4.y);
        s.z = f2bf((y1[cti][nt][2] - mu[nt]) * rs[nt] * g4.z + be4.z);
        s.w = f2bf((y1[cti][nt][3] - mu[nt]) * rs[nt] * g4.w + be4.w);
        *(short4*)(&SP[(nt * 16 + l15) * 200 + cb + cti * 16 + quad * 4]) = s;
      }
    }
    __syncthreads();               // D: y1n ready

    // ---- G2: y2 = W1 . y1n^T ; gelu -> HB (separate buffer) ----
    v4f y2[3][2];
#pragma unroll
    for (int cti = 0; cti < 3; cti++)
#pragma unroll
      for (int nt = 0; nt < 2; nt++) y2[cti][nt] = vzero;
#pragma unroll
    for (int ks = 0; ks < 6; ks++) {
      v8s bh[2];
#pragma unroll
      for (int nt = 0; nt < 2; nt++)
        bh[nt] = *(const v8s*)(SP + (nt * 16 + l15) * 200 + ks * 32 + quad * 8);
#pragma unroll
      for (int cti = 0; cti < 3; cti++) {
        v8s a = *(const v8s*)(W1_bf + (size_t)(cb + cti * 16 + l15) * 192 + ks * 32 + quad * 8);
#pragma unroll
        for (int nt = 0; nt < 2; nt++)
          y2[cti][nt] = __builtin_amdgcn_mfma_f32_16x16x32_bf16(a, bh[nt], y2[cti][nt], 0, 0, 0);
      }
    }
#pragma unroll
    for (int cti = 0; cti < 3; cti++) {
      float4 b14 = *(const float4*)(b1 + cb + cti * 16 + quad * 4);
#pragma unroll
      for (int nt = 0; nt < 2; nt++) {
        float vv[4] = {y2[cti][nt][0] + b14.x, y2[cti][nt][1] + b14.y,
                       y2[cti][nt][2] + b14.z, y2[cti][nt][3] + b14.w};
        short sv[4];
#pragma unroll
        for (int r = 0; r < 4; r++) {
          float v = vv[r];
          float t = 0.79788456080286536f * (v + 0.044715f * v * v * v);
          float e = __expf(2.0f * t);
          float th = 1.0f - 2.0f / (e + 1.0f);
          sv[r] = f2bf(0.5f * v * (1.0f + th));
        }
        short4 s;
        s.x = sv[0]; s.y = sv[1]; s.z = sv[2]; s.w = sv[3];
        *(short4*)(&HB[(nt * 16 + l15) * 200 + cb + cti * 16 + quad * 4]) = s;
      }
    }
    __syncthreads();               // E: h ready; G2 SP reads done

    // ---- G3: acc += W2 . h^T (from HB) ----
#pragma unroll
    for (int ks = 0; ks < 6; ks++) {
      v8s bh[2];
#pragma unroll
      for (int nt = 0; nt < 2; nt++)
        bh[nt] = *(const v8s*)(HB + (nt * 16 + l15) * 200 + ks * 32 + quad * 8);
#pragma unroll
      for (int cti = 0; cti < 3; cti++) {
        v8s a = *(const v8s*)(W2_bf + (size_t)(cb + cti * 16 + l15) * 192 + ks * 32 + quad * 8);
#pragma unroll
        for (int nt = 0; nt < 2; nt++)
          acc[cti][nt] = __builtin_amdgcn_mfma_f32_16x16x32_bf16(a, bh[nt], acc[cti][nt], 0, 0, 0);
      }
    }
  }

  // ---- epilogue: stage acc/6 to LDS (f32), write full contiguous rows ----
  // SPf: 16 rows x pitch 196 f32 = 12544 B <= 12800 B (SP).
  float* SPf = (float*)SP;
#pragma unroll
  for (int pass = 0; pass < 2; pass++) {
    __syncthreads();               // SP/HB reads done (pass 0) / prior pass copy done
#pragma unroll
    for (int cti = 0; cti < 3; cti++) {
      float4 o4;
      o4.x = acc[cti][pass][0] * (1.0f / 6.0f);
      o4.y = acc[cti][pass][1] * (1.0f / 6.0f);
      o4.z = acc[cti][pass][2] * (1.0f / 6.0f);
      o4.w = acc[cti][pass][3] * (1.0f / 6.0f);
      *(float4*)(&SPf[l15 * 196 + cb + cti * 16 + quad * 4]) = o4;
    }
    __syncthreads();
    // 16 rows x 48 float4; both output halves written from one x read
    for (int c = tid; c < 768; c += 256) {
      int r16 = c / 48, col4 = (c - r16 * 48) * 4;
      int row = half * 32 + pass * 16 + r16;
      size_t nrow = (size_t)b * 384 + (size_t)i * 64 + row;
      float4 xv = *(const float4*)(x + nrow * DIM + col4);
      float4 b24 = *(const float4*)(b2 + col4);
      float4 av = *(const float4*)(&SPf[r16 * 196 + col4]);
      float4 o4;
      o4.x = xv.x + av.x + b24.x;
      o4.y = xv.y + av.y + b24.y;
      o4.z = xv.z + av.z + b24.z;
      o4.w = xv.w + av.w + b24.w;
      *(float4*)(out + nrow * 384 + col4) = xv;             // x half bit-exact
      *(float4*)(out + nrow * 384 + 192 + col4) = o4;
    }
  }
}

extern "C" void kernel_launch(void* const* d_in, const int* in_sizes, int n_in,
                              void* d_out, int out_size, void* d_ws, size_t ws_size,
                              hipStream_t stream) {
  (void)in_sizes; (void)n_in; (void)out_size; (void)ws_size;
  const float* x     = (const float*)d_in[0];
  const float* Wqkv  = (const float*)d_in[1];
  const float* Wproj = (const float*)d_in[2];
  const float* bproj = (const float*)d_in[3];
  const float* gamma = (const float*)d_in[4];
  const float* beta  = (const float*)d_in[5];
  const float* W1    = (const float*)d_in[6];
  const float* b1    = (const float*)d_in[7];
  const float* W2    = (const float*)d_in[8];
  const float* b2    = (const float*)d_in[9];
  float* out = (float*)d_out;

  // workspace: weights bf16 + pos f32 + Q/K/Vt bf16
  short* Wqkv_bf  = (short*)d_ws;                 // 576*192
  short* Wproj_bf = Wqkv_bf + 110592;             // 192*384
  short* W1_bf    = Wproj_bf + 73728;             // 192*192
  short* W2_bf    = W1_bf + 36864;                // 192*192
  float* pos_f    = (float*)(W2_bf + 36864);      // 64*192 f32
  short* Qb       = (short*)(pos_f + 12288);      // [b][t][hw][ch]
  short* Kb       = Qb + 9437184;                 // [b][t][hw][ch]
  short* Vtb      = Kb + 9437184;                 // [b][t][ch][hw]

  prep_kernel<<<dim3(264), dim3(256), 0, stream>>>(
      Wqkv, Wproj, W1, W2, Wqkv_bf, Wproj_bf, W1_bf, W2_bf, pos_f);
  qkv_kernel<<<dim3(TT * NB), dim3(256), 0, stream>>>(x, pos_f, Wqkv_bf, Qb, Kb, Vtb);
  fused_all<<<dim3(TT * NB * 2), dim3(256), 0, stream>>>(
      x, Qb, Kb, Vtb, Wproj_bf, W1_bf, W2_bf, bproj, gamma, beta, b1, b2, out);
}

// Round 9
// 561.840 us; speedup vs baseline: 1.6562x; 1.0131x over previous
//
#include <hip/hip_runtime.h>
#include <cmath>

#define TT   6
#define NB   128
#define DIM  192
#define SCALE 0.17677669529663687f

typedef __attribute__((ext_vector_type(8))) short v8s;
typedef __attribute__((ext_vector_type(4))) float v4f;

__device__ __forceinline__ short f2bf(float f) {
  union { float f; unsigned u; } v; v.f = f;
  unsigned r = v.u + 0x7fffu + ((v.u >> 16) & 1u);
  return (short)(r >> 16);
}

// ---- fused prep: bf16 weight conversion + sine position table, one launch ----
__global__ void prep_kernel(const float* __restrict__ Wqkv, const float* __restrict__ Wproj,
                            const float* __restrict__ W1, const float* __restrict__ W2,
                            short* __restrict__ dWqkv, short* __restrict__ dWproj,
                            short* __restrict__ dW1, short* __restrict__ dW2,
                            float* __restrict__ pos) {
  int idx = blockIdx.x * 256 + threadIdx.x;
  const float* src = nullptr; short* dst = nullptr; int off = 0;
  if (idx < 27648)      { src = Wqkv;  dst = dWqkv;  off = idx; }
  else if (idx < 46080) { src = Wproj; dst = dWproj; off = idx - 27648; }
  else if (idx < 55296) { src = W1;    dst = dW1;    off = idx - 46080; }
  else if (idx < 64512) { src = W2;    dst = dW2;    off = idx - 55296; }
  else if (idx < 67584) {
    int p0 = (idx - 64512) * 4;
    float4 r;
    float* rp = (float*)&r;
#pragma unroll
    for (int jj = 0; jj < 4; jj++) {
      int p = p0 + jj;
      int row = p / 192, c = p - row * 192;
      int e  = (c < 96) ? (row >> 3) : (row & 7);
      int cc = (c < 96) ? c : c - 96;
      int m = cc >> 1;
      float embed = (float)(e + 1) * (6.283185307179586f / 8.000001f);
      float dt = powf(10000.0f, (float)m * (1.0f / 48.0f));
      float ang = embed / dt;
      rp[jj] = (cc & 1) ? cosf(ang) : sinf(ang);
    }
    *(float4*)(pos + p0) = r;
    return;
  } else return;
  const float* s = src + off * 4;
  short4 r;
  r.x = f2bf(s[0]); r.y = f2bf(s[1]); r.z = f2bf(s[2]); r.w = f2bf(s[3]);
  *(short4*)(dst + off * 4) = r;
}

// ---- QKV pre-kernel: one block per (b,t). Q,K row-major [hw][ch]; V transposed [ch][hw].
// Grid swizzled with the SAME XCD mapping as fused_all (r4-verified: FETCH 186->78MB).
__global__ __launch_bounds__(256) void qkv_kernel(
    const float* __restrict__ x, const float* __restrict__ pos,
    const short* __restrict__ Wqkv_bf,
    short* __restrict__ Qb, short* __restrict__ Kb, short* __restrict__ Vtb) {
  __shared__ short XP[64 * 200];
  int bid = blockIdx.x;
  int xcd = bid & 7, idx = bid >> 3;   // 96 blocks per XCD
  int bq = idx / TT;
  int b = xcd * 16 + bq, t = idx - bq * TT;
  int tid = threadIdx.x, w = tid >> 6, lane = tid & 63;
  int l15 = lane & 15, quad = lane >> 4;
  const float* xrow = x + (size_t)(b * (TT * 64) + t * 64) * DIM;
  for (int c = tid; c < 64 * 24; c += 256) {
    int row = c / 24, col8 = (c - (c / 24) * 24) * 8;
    const float* xs = xrow + row * DIM + col8;
    const float* pp = pos + row * DIM + col8;
    v8s r8;
#pragma unroll
    for (int jj = 0; jj < 8; jj++) r8[jj] = f2bf(xs[jj] + pp[jj]);
    *(v8s*)(XP + row * 200 + col8) = r8;
  }
  __syncthreads();
  const v4f vzero = {0.f, 0.f, 0.f, 0.f};
  size_t obase = (size_t)(b * TT + t) * 64 * DIM;
#pragma unroll
  for (int cti = 0; cti < 9; cti++) {
    int r0 = w * 144 + cti * 16;
    v4f acc[4] = {vzero, vzero, vzero, vzero};
#pragma unroll
    for (int ks = 0; ks < 6; ks++) {
      v8s a = *(const v8s*)(Wqkv_bf + (size_t)(r0 + l15) * 192 + ks * 32 + quad * 8);
#pragma unroll
      for (int nt = 0; nt < 4; nt++) {
        v8s bb = *(const v8s*)(XP + (nt * 16 + l15) * 200 + ks * 32 + quad * 8);
        acc[nt] = __builtin_amdgcn_mfma_f32_16x16x32_bf16(a, bb, acc[nt], 0, 0, 0);
      }
    }
    int R = r0 + quad * 4;
#pragma unroll
    for (int nt = 0; nt < 4; nt++) {
      int hw = nt * 16 + l15;
      if (R < 192) {
        short4 s;
        s.x = f2bf(acc[nt][0] * SCALE); s.y = f2bf(acc[nt][1] * SCALE);
        s.z = f2bf(acc[nt][2] * SCALE); s.w = f2bf(acc[nt][3] * SCALE);
        *(short4*)(Qb + obase + (size_t)hw * 192 + R) = s;
      } else if (R < 384) {
        short4 s;
        s.x = f2bf(acc[nt][0]); s.y = f2bf(acc[nt][1]);
        s.z = f2bf(acc[nt][2]); s.w = f2bf(acc[nt][3]);
        *(short4*)(Kb + obase + (size_t)hw * 192 + (R - 192)) = s;
      } else {
#pragma unroll
        for (int r = 0; r < 4; r++)
          Vtb[obase + (size_t)(R - 384 + r) * 64 + hw] = f2bf(acc[nt][r]);
      }
    }
  }
}

// ---- main fused kernel: one block per (i,b,half), 256 threads (4 waves), 32 hw rows.
// r8 structure (best clean run: 470us, no spill) with ONE change: the attention
// P-transpose goes through registers (cvt_pk_bf16 + shfl quad-transpose, r4-verified
// spill-free) instead of the Pl LDS round-trip. This deletes the 2 lgkmcnt(0)+
// "memory" fences per head (36/block) that were blocking the compiler from
// hoisting K/V loads across heads -- the attn phase was the longest serial chain
// while all pipes sat ~70% idle.
__global__ __launch_bounds__(256, 4) void fused_all(
    const float* __restrict__ x,
    const short* __restrict__ Qb, const short* __restrict__ Kb,
    const short* __restrict__ Vtb,
    const short* __restrict__ Wproj_bf, const short* __restrict__ W1_bf,
    const short* __restrict__ W2_bf,
    const float* __restrict__ bproj, const float* __restrict__ gamma,
    const float* __restrict__ beta, const float* __restrict__ b1,
    const float* __restrict__ b2,
    float* __restrict__ out) {
  __shared__ short SP[32 * 200];     // Xi staging / o / y1n; f32 acc staging in epilogue
  __shared__ short HB[32 * 200];     // gelu output h
  __shared__ float LNp[32][4][2];    // LN partials: [row][wc][s1,s2]

  // XCD swizzle: 12 blocks (6 i x 2 half) sharing b land on one XCD
  int bid = blockIdx.x;
  int xcd = bid & 7, idx = bid >> 3;     // 192 per XCD
  int bq = idx / 12;
  int rem = idx - bq * 12;
  int i = rem >> 1, half = rem & 1;
  int b = xcd * 16 + bq;

  int tid = threadIdx.x, w = tid >> 6, lane = tid & 63;
  int l15 = lane & 15, quad = lane >> 4;
  int wc = w;                        // GEMM channel slice
  int qt = w & 1, hg = w >> 1;       // attention: q-tile, head-group
  int cb = wc * 48;
  const v4f vzero = {0.f, 0.f, 0.f, 0.f};

  // ---- stage Xi (x.view rows, this half) as bf16 into SP ----
  const float* xi = x + (size_t)((i * NB + b) * 64 + half * 32) * DIM;
  for (int c = tid; c < 32 * 24; c += 256) {
    int row = c / 24, col8 = (c - (c / 24) * 24) * 8;
    const float* xs = xi + row * DIM + col8;
    v8s r8;
#pragma unroll
    for (int jj = 0; jj < 8; jj++) r8[jj] = f2bf(xs[jj]);
    *(v8s*)(SP + row * 200 + col8) = r8;
  }

  // ---- hoist Q fragments (j-invariant): wave's 16 q-rows x its 3 heads ----
  const short* Qi = Qb + (size_t)(b * TT + i) * 64 * DIM;
  v8s qa[3];
#pragma unroll
  for (int hh = 0; hh < 3; hh++)
    qa[hh] = *(const v8s*)(Qi + (size_t)(half * 32 + qt * 16 + l15) * 192 + (hg * 3 + hh) * 32 + quad * 8);

  v4f acc[3][2];
#pragma unroll
  for (int cti = 0; cti < 3; cti++)
#pragma unroll
    for (int nt = 0; nt < 2; nt++) acc[cti][nt] = vzero;

  __syncthreads();                   // Xi staged

  // ---- y1x = Wproj[:,192:384] . Xi^T (j-invariant, registers) ----
  v4f y1x[3][2];
#pragma unroll
  for (int cti = 0; cti < 3; cti++)
#pragma unroll
    for (int nt = 0; nt < 2; nt++) y1x[cti][nt] = vzero;
#pragma unroll
  for (int ks = 0; ks < 6; ks++) {
    v8s bxi[2];
#pragma unroll
    for (int nt = 0; nt < 2; nt++)
      bxi[nt] = *(const v8s*)(SP + (nt * 16 + l15) * 200 + ks * 32 + quad * 8);
#pragma unroll
    for (int cti = 0; cti < 3; cti++) {
      v8s a = *(const v8s*)(Wproj_bf + (size_t)(cb + cti * 16 + l15) * 384 + 192 + ks * 32 + quad * 8);
#pragma unroll
      for (int nt = 0; nt < 2; nt++)
        y1x[cti][nt] = __builtin_amdgcn_mfma_f32_16x16x32_bf16(a, bxi[nt], y1x[cti][nt], 0, 0, 0);
    }
  }

  int srcA = l15 + ((lane & 16) << 1);   // l15 + 32*(quad&1)
  int srcB = srcA + 16;
  bool hiq = (lane & 32) != 0;           // quad >= 2

  for (int j = 0; j < TT; j++) {
    __syncthreads();               // A: j=0: y1x SP reads done; j>0: G2 SP reads done
    {
      const short* Kj = Kb + (size_t)(b * TT + j) * 64 * DIM;
      const short* Vj = Vtb + (size_t)(b * TT + j) * 64 * DIM;
#pragma unroll
      for (int hh = 0; hh < 3; hh++) {
        int h = hg * 3 + hh;
        v4f S[4];
#pragma unroll
        for (int cta = 0; cta < 4; cta++) {
          v8s akq = *(const v8s*)(Kj + (size_t)(cta * 16 + l15) * 192 + h * 32 + quad * 8);
          S[cta] = __builtin_amdgcn_mfma_f32_16x16x32_bf16(akq, qa[hh], vzero, 0, 0, 0);
        }
        float mx = -1e30f;
#pragma unroll
        for (int cta = 0; cta < 4; cta++)
#pragma unroll
          for (int r = 0; r < 4; r++) mx = fmaxf(mx, S[cta][r]);
        mx = fmaxf(mx, __shfl_xor(mx, 16, 64));
        mx = fmaxf(mx, __shfl_xor(mx, 32, 64));
        float sum = 0.f;
#pragma unroll
        for (int cta = 0; cta < 4; cta++)
#pragma unroll
          for (int r = 0; r < 4; r++) {
            float e = __expf(S[cta][r] - mx);
            S[cta][r] = e; sum += e;
          }
        sum += __shfl_xor(sum, 16, 64);
        sum += __shfl_xor(sum, 32, 64);
        float inv = 1.0f / sum;
        // pack P to bf16 pairs (named scalars -- r4-verified spill-free)
        unsigned pk00, pk01, pk10, pk11, pk20, pk21, pk30, pk31;
        {
          float a0 = S[0][0] * inv, a1 = S[0][1] * inv, a2 = S[0][2] * inv, a3 = S[0][3] * inv;
          __asm__("v_cvt_pk_bf16_f32 %0, %1, %2" : "=v"(pk00) : "v"(a0), "v"(a1));
          __asm__("v_cvt_pk_bf16_f32 %0, %1, %2" : "=v"(pk01) : "v"(a2), "v"(a3));
          float b0 = S[1][0] * inv, b1_ = S[1][1] * inv, b2_ = S[1][2] * inv, b3 = S[1][3] * inv;
          __asm__("v_cvt_pk_bf16_f32 %0, %1, %2" : "=v"(pk10) : "v"(b0), "v"(b1_));
          __asm__("v_cvt_pk_bf16_f32 %0, %1, %2" : "=v"(pk11) : "v"(b2_), "v"(b3));
          float c0 = S[2][0] * inv, c1 = S[2][1] * inv, c2 = S[2][2] * inv, c3 = S[2][3] * inv;
          __asm__("v_cvt_pk_bf16_f32 %0, %1, %2" : "=v"(pk20) : "v"(c0), "v"(c1));
          __asm__("v_cvt_pk_bf16_f32 %0, %1, %2" : "=v"(pk21) : "v"(c2), "v"(c3));
          float d0 = S[3][0] * inv, d1 = S[3][1] * inv, d2 = S[3][2] * inv, d3 = S[3][3] * inv;
          __asm__("v_cvt_pk_bf16_f32 %0, %1, %2" : "=v"(pk30) : "v"(d0), "v"(d1));
          __asm__("v_cvt_pk_bf16_f32 %0, %1, %2" : "=v"(pk31) : "v"(d2), "v"(d3));
        }
        // quad-transpose to PV B-fragment layout (register-only; no LDS, no fences)
        union { unsigned u[4]; v8s v; } B0, B1;
        {
          unsigned ta = (unsigned)__shfl((int)pk00, srcA), tb = (unsigned)__shfl((int)pk10, srcA);
          B0.u[0] = hiq ? tb : ta;
          ta = (unsigned)__shfl((int)pk01, srcA); tb = (unsigned)__shfl((int)pk11, srcA);
          B0.u[1] = hiq ? tb : ta;
          ta = (unsigned)__shfl((int)pk00, srcB); tb = (unsigned)__shfl((int)pk10, srcB);
          B0.u[2] = hiq ? tb : ta;
          ta = (unsigned)__shfl((int)pk01, srcB); tb = (unsigned)__shfl((int)pk11, srcB);
          B0.u[3] = hiq ? tb : ta;
          ta = (unsigned)__shfl((int)pk20, srcA); tb = (unsigned)__shfl((int)pk30, srcA);
          B1.u[0] = hiq ? tb : ta;
          ta = (unsigned)__shfl((int)pk21, srcA); tb = (unsigned)__shfl((int)pk31, srcA);
          B1.u[1] = hiq ? tb : ta;
          ta = (unsigned)__shfl((int)pk20, srcB); tb = (unsigned)__shfl((int)pk30, srcB);
          B1.u[2] = hiq ? tb : ta;
          ta = (unsigned)__shfl((int)pk21, srcB); tb = (unsigned)__shfl((int)pk31, srcB);
          B1.u[3] = hiq ? tb : ta;
        }
        // PV
#pragma unroll
        for (int ct2 = 0; ct2 < 2; ct2++) {
          v8s av0 = *(const v8s*)(Vj + (size_t)(h * 32 + ct2 * 16 + l15) * 64 + quad * 8);
          v8s av1 = *(const v8s*)(Vj + (size_t)(h * 32 + ct2 * 16 + l15) * 64 + 32 + quad * 8);
          v4f o = __builtin_amdgcn_mfma_f32_16x16x32_bf16(av0, B0.v, vzero, 0, 0, 0);
          o = __builtin_amdgcn_mfma_f32_16x16x32_bf16(av1, B1.v, o, 0, 0, 0);
          short4 s;
          s.x = f2bf(o[0]); s.y = f2bf(o[1]); s.z = f2bf(o[2]); s.w = f2bf(o[3]);
          *(short4*)(&SP[(qt * 16 + l15) * 200 + h * 32 + ct2 * 16 + quad * 4]) = s;
        }
      }
    }
    __syncthreads();               // B: o ready

    // ---- G1: y1 = y1x + Wproj[:,0:192] . o^T ----
    v4f y1[3][2];
#pragma unroll
    for (int cti = 0; cti < 3; cti++)
#pragma unroll
      for (int nt = 0; nt < 2; nt++) y1[cti][nt] = y1x[cti][nt];
#pragma unroll
    for (int ks = 0; ks < 6; ks++) {
      v8s bo[2];
#pragma unroll
      for (int nt = 0; nt < 2; nt++)
        bo[nt] = *(const v8s*)(SP + (nt * 16 + l15) * 200 + ks * 32 + quad * 8);
#pragma unroll
      for (int cti = 0; cti < 3; cti++) {
        v8s a = *(const v8s*)(Wproj_bf + (size_t)(cb + cti * 16 + l15) * 384 + ks * 32 + quad * 8);
#pragma unroll
        for (int nt = 0; nt < 2; nt++)
          y1[cti][nt] = __builtin_amdgcn_mfma_f32_16x16x32_bf16(a, bo[nt], y1[cti][nt], 0, 0, 0);
      }
    }
#pragma unroll
    for (int cti = 0; cti < 3; cti++) {
      float4 bp4 = *(const float4*)(bproj + cb + cti * 16 + quad * 4);
#pragma unroll
      for (int nt = 0; nt < 2; nt++) {
        y1[cti][nt][0] += bp4.x; y1[cti][nt][1] += bp4.y;
        y1[cti][nt][2] += bp4.z; y1[cti][nt][3] += bp4.w;
      }
    }
#pragma unroll
    for (int nt = 0; nt < 2; nt++) {
      float s1 = 0.f, s2 = 0.f;
#pragma unroll
      for (int cti = 0; cti < 3; cti++)
#pragma unroll
        for (int r = 0; r < 4; r++) { float v = y1[cti][nt][r]; s1 += v; s2 += v * v; }
      s1 += __shfl_xor(s1, 16, 64); s2 += __shfl_xor(s2, 16, 64);
      s1 += __shfl_xor(s1, 32, 64); s2 += __shfl_xor(s2, 32, 64);
      if (quad == 0) {
        LNp[nt * 16 + l15][wc][0] = s1;
        LNp[nt * 16 + l15][wc][1] = s2;
      }
    }
    __syncthreads();               // C: partials visible; G1 SP reads done
    float mu[2], rs[2];
#pragma unroll
    for (int nt = 0; nt < 2; nt++) {
      int row = nt * 16 + l15;
      float s1 = 0.f, s2 = 0.f;
#pragma unroll
      for (int ww = 0; ww < 4; ww++) { s1 += LNp[row][ww][0]; s2 += LNp[row][ww][1]; }
      float m = s1 * (1.0f / 192.0f);
      mu[nt] = m; rs[nt] = rsqrtf(s2 * (1.0f / 192.0f) - m * m + 1e-5f);
    }
#pragma unroll
    for (int cti = 0; cti < 3; cti++) {
      float4 g4 = *(const float4*)(gamma + cb + cti * 16 + quad * 4);
      float4 be4 = *(const float4*)(beta + cb + cti * 16 + quad * 4);
#pragma unroll
      for (int nt = 0; nt < 2; nt++) {
        short4 s;
        s.x = f2bf((y1[cti][nt][0] - mu[nt]) * rs[nt] * g4.x + be4.x);
        s.y = f2bf((y1[cti][nt][1] - mu[nt]) * rs[nt] * g4.y + be4.y);
        s.z = f2bf((y1[cti][nt][2] - mu[nt]) * rs[nt] * g4.z + be4.z);
        s.w = f2bf((y1[cti][nt][3] - mu[nt]) * rs[nt] * g4.w + be4.w);
        *(short4*)(&SP[(nt * 16 + l15) * 200 + cb + cti * 16 + quad * 4]) = s;
      }
    }
    __syncthreads();               // D: y1n ready

    // ---- G2: y2 = W1 . y1n^T ; gelu -> HB (separate buffer) ----
    v4f y2[3][2];
#pragma unroll
    for (int cti = 0; cti < 3; cti++)
#pragma unroll
      for (int nt = 0; nt < 2; nt++) y2[cti][nt] = vzero;
#pragma unroll
    for (int ks = 0; ks < 6; ks++) {
      v8s bh[2];
#pragma unroll
      for (int nt = 0; nt < 2; nt++)
        bh[nt] = *(const v8s*)(SP + (nt * 16 + l15) * 200 + ks * 32 + quad * 8);
#pragma unroll
      for (int cti = 0; cti < 3; cti++) {
        v8s a = *(const v8s*)(W1_bf + (size_t)(cb + cti * 16 + l15) * 192 + ks * 32 + quad * 8);
#pragma unroll
        for (int nt = 0; nt < 2; nt++)
          y2[cti][nt] = __builtin_amdgcn_mfma_f32_16x16x32_bf16(a, bh[nt], y2[cti][nt], 0, 0, 0);
      }
    }
#pragma unroll
    for (int cti = 0; cti < 3; cti++) {
      float4 b14 = *(const float4*)(b1 + cb + cti * 16 + quad * 4);
#pragma unroll
      for (int nt = 0; nt < 2; nt++) {
        float vv[4] = {y2[cti][nt][0] + b14.x, y2[cti][nt][1] + b14.y,
                       y2[cti][nt][2] + b14.z, y2[cti][nt][3] + b14.w};
        short sv[4];
#pragma unroll
        for (int r = 0; r < 4; r++) {
          float v = vv[r];
          float t = 0.79788456080286536f * (v + 0.044715f * v * v * v);
          float e = __expf(2.0f * t);
          float th = 1.0f - 2.0f / (e + 1.0f);
          sv[r] = f2bf(0.5f * v * (1.0f + th));
        }
        short4 s;
        s.x = sv[0]; s.y = sv[1]; s.z = sv[2]; s.w = sv[3];
        *(short4*)(&HB[(nt * 16 + l15) * 200 + cb + cti * 16 + quad * 4]) = s;
      }
    }
    __syncthreads();               // E: h ready; G2 SP reads done

    // ---- G3: acc += W2 . h^T (from HB) ----
#pragma unroll
    for (int ks = 0; ks < 6; ks++) {
      v8s bh[2];
#pragma unroll
      for (int nt = 0; nt < 2; nt++)
        bh[nt] = *(const v8s*)(HB + (nt * 16 + l15) * 200 + ks * 32 + quad * 8);
#pragma unroll
      for (int cti = 0; cti < 3; cti++) {
        v8s a = *(const v8s*)(W2_bf + (size_t)(cb + cti * 16 + l15) * 192 + ks * 32 + quad * 8);
#pragma unroll
        for (int nt = 0; nt < 2; nt++)
          acc[cti][nt] = __builtin_amdgcn_mfma_f32_16x16x32_bf16(a, bh[nt], acc[cti][nt], 0, 0, 0);
      }
    }
  }

  // ---- epilogue: stage acc/6 to LDS (f32), write full contiguous rows ----
  // SPf: 16 rows x pitch 196 f32 = 12544 B <= 12800 B (SP).
  float* SPf = (float*)SP;
#pragma unroll
  for (int pass = 0; pass < 2; pass++) {
    __syncthreads();               // SP/HB reads done (pass 0) / prior pass copy done
#pragma unroll
    for (int cti = 0; cti < 3; cti++) {
      float4 o4;
      o4.x = acc[cti][pass][0] * (1.0f / 6.0f);
      o4.y = acc[cti][pass][1] * (1.0f / 6.0f);
      o4.z = acc[cti][pass][2] * (1.0f / 6.0f);
      o4.w = acc[cti][pass][3] * (1.0f / 6.0f);
      *(float4*)(&SPf[l15 * 196 + cb + cti * 16 + quad * 4]) = o4;
    }
    __syncthreads();
    // 16 rows x 48 float4; both output halves written from one x read
    for (int c = tid; c < 768; c += 256) {
      int r16 = c / 48, col4 = (c - r16 * 48) * 4;
      int row = half * 32 + pass * 16 + r16;
      size_t nrow = (size_t)b * 384 + (size_t)i * 64 + row;
      float4 xv = *(const float4*)(x + nrow * DIM + col4);
      float4 b24 = *(const float4*)(b2 + col4);
      float4 av = *(const float4*)(&SPf[r16 * 196 + col4]);
      float4 o4;
      o4.x = xv.x + av.x + b24.x;
      o4.y = xv.y + av.y + b24.y;
      o4.z = xv.z + av.z + b24.z;
      o4.w = xv.w + av.w + b24.w;
      *(float4*)(out + nrow * 384 + col4) = xv;             // x half bit-exact
      *(float4*)(out + nrow * 384 + 192 + col4) = o4;
    }
  }
}

extern "C" void kernel_launch(void* const* d_in, const int* in_sizes, int n_in,
                              void* d_out, int out_size, void* d_ws, size_t ws_size,
                              hipStream_t stream) {
  (void)in_sizes; (void)n_in; (void)out_size; (void)ws_size;
  const float* x     = (const float*)d_in[0];
  const float* Wqkv  = (const float*)d_in[1];
  const float* Wproj = (const float*)d_in[2];
  const float* bproj = (const float*)d_in[3];
  const float* gamma = (const float*)d_in[4];
  const float* beta  = (const float*)d_in[5];
  const float* W1    = (const float*)d_in[6];
  const float* b1    = (const float*)d_in[7];
  const float* W2    = (const float*)d_in[8];
  const float* b2    = (const float*)d_in[9];
  float* out = (float*)d_out;

  // workspace: weights bf16 + pos f32 + Q/K/Vt bf16
  short* Wqkv_bf  = (short*)d_ws;                 // 576*192
  short* Wproj_bf = Wqkv_bf + 110592;             // 192*384
  short* W1_bf    = Wproj_bf + 73728;             // 192*192
  short* W2_bf    = W1_bf + 36864;                // 192*192
  float* pos_f    = (float*)(W2_bf + 36864);      // 64*192 f32
  short* Qb       = (short*)(pos_f + 12288);      // [b][t][hw][ch]
  short* Kb       = Qb + 9437184;                 // [b][t][hw][ch]
  short* Vtb      = Kb + 9437184;                 // [b][t][ch][hw]

  prep_kernel<<<dim3(264), dim3(256), 0, stream>>>(
      Wqkv, Wproj, W1, W2, Wqkv_bf, Wproj_bf, W1_bf, W2_bf, pos_f);
  qkv_kernel<<<dim3(TT * NB), dim3(256), 0, stream>>>(x, pos_f, Wqkv_bf, Qb, Kb, Vtb);
  fused_all<<<dim3(TT * NB * 2), dim3(256), 0, stream>>>(
      x, Qb, Kb, Vtb, Wproj_bf, W1_bf, W2_bf, bproj, gamma, beta, b1, b2, out);
}